// Round 5
// baseline (1180.606 us; speedup 1.0000x reference)
//
#include <hip/hip_runtime.h>

typedef __bf16 bf16x8 __attribute__((ext_vector_type(8)));
typedef __bf16 bf16x4 __attribute__((ext_vector_type(4)));
typedef float  f32x4  __attribute__((ext_vector_type(4)));

typedef __attribute__((address_space(3))) unsigned int        lds_u32_t;
typedef const __attribute__((address_space(1))) unsigned int  glob_u32_t;

// ==================== Kernel 1: x fp32 -> bf16 ====================
__global__ __launch_bounds__(256)
void cvt_x_bf16(const float* __restrict__ X, __bf16* __restrict__ XB, long long n8)
{
    long long i = (long long)blockIdx.x * 256 + threadIdx.x;
    if (i >= n8) return;
    const float4* src = (const float4*)X + 2 * i;
    float4 a = src[0], b = src[1];
    bf16x8 v = { (__bf16)a.x, (__bf16)a.y, (__bf16)a.z, (__bf16)a.w,
                 (__bf16)b.x, (__bf16)b.y, (__bf16)b.z, (__bf16)b.w };
    *(bf16x8*)(XB + 8 * i) = v;
}

// ==================== Kernel 2: dequant -> W^T bf16 [N][K] ====================
__global__ __launch_bounds__(256)
void dequant_wt(const unsigned int* __restrict__ QW,
                const unsigned int* __restrict__ QZ,
                const float* __restrict__ SC,
                __bf16* __restrict__ WT,
                const int N, const int K)
{
    __shared__ __bf16 T[256 * 64];
    const int tid = threadIdx.x;
    const int nK  = K >> 6;
    const int n0  = (blockIdx.x / nK) * 256;
    const int k0  = (blockIdx.x % nK) * 64;

    const int n = n0 + tid;
    const int g = k0 >> 7;
    const float s = SC[g * N + n];
    const unsigned int qzv = QZ[g * (N >> 3) + (n >> 3)];
    const float nz = (float)((qzv >> ((n & 7) * 4)) & 15) * s;
    const int qr0 = k0 >> 3;

    #pragma unroll
    for (int i = 0; i < 8; ++i) {
        const unsigned int w32 = QW[(size_t)(qr0 + i) * N + n];
        bf16x8 v;
        #pragma unroll
        for (int j = 0; j < 8; ++j)
            v[j] = (__bf16)((float)((w32 >> (4 * j)) & 15) * s - nz);
        *(bf16x8*)((char*)T + tid * 128 + ((i ^ (tid & 7)) << 4)) = v;
    }
    __syncthreads();
    #pragma unroll
    for (int it = 0; it < 8; ++it) {
        const int r = it * 32 + (tid >> 3);
        const int c = tid & 7;
        bf16x8 v = *(bf16x8*)((char*)T + r * 128 + ((c ^ (r & 7)) << 4));
        *(bf16x8*)(WT + (size_t)(n0 + r) * K + k0 + c * 8) = v;
    }
}

// ==================== Kernel 3: 256x256 deep-pipelined bf16 B^T GEMM ====================
// BM=BN=256, BK=64; 8 waves (2M x 4N); per-wave 128x64 out, acc[8][4].
// LDS 128 KiB dynamic: Abuf0|Abuf1|Bbuf0|Bbuf1, each 32 KiB, split into two
// k-halves [h][256 rows][32 k] bf16, XOR-chunk swizzled (involution both sides).
// Staging: ONE k-half-stage (2 gload_lds/thread) per phase, issued 3-6 phases
// before its consuming wait:
//   x.P0 -> (x+1).A-h1 | x.P1 -> (x+1).B-h1 | x.P2 -> (x+2).A-h0 | x.P3 -> (x+2).B-h0
// Waits: vmcnt(10) at P0 and P2 (tail-peeled 10/8 then 4/0) - never 0 in steady state.

#define RD_A(b_, ks, mh)                                                          \
  { _Pragma("unroll")                                                             \
    for (int mi = 0; mi < 4; ++mi) {                                              \
      const int r = wmRow + ((mh) * 4 + mi) * 16 + l15;                           \
      af[mi] = *(const bf16x8*)(smem + (b_) * 32768 + (ks) * 16384 + r * 64 +     \
                                (swz << 4));                                      \
    } }

#define RD_B(b_, ks)                                                              \
  { _Pragma("unroll")                                                             \
    for (int ni = 0; ni < 4; ++ni) {                                              \
      const int r = wnRow + ni * 16 + l15;                                        \
      bfr[ni] = *(const bf16x8*)(smem + 65536 + (b_) * 32768 + (ks) * 16384 +     \
                                 r * 64 + (swz << 4));                            \
    } }

#define PH_MFMA(mh)                                                               \
  {                                                                               \
    asm volatile("s_waitcnt lgkmcnt(0)" ::: "memory");                            \
    __builtin_amdgcn_sched_barrier(0);                                            \
    __builtin_amdgcn_s_setprio(1);                                                \
    _Pragma("unroll")                                                             \
    for (int mi = 0; mi < 4; ++mi)                                                \
      _Pragma("unroll")                                                           \
      for (int ni = 0; ni < 4; ++ni)                                              \
        acc[(mh) * 4 + mi][ni] = __builtin_amdgcn_mfma_f32_16x16x32_bf16(         \
            af[mi], bfr[ni], acc[(mh) * 4 + mi][ni], 0, 0, 0);                    \
    __builtin_amdgcn_s_setprio(0);                                                \
    __builtin_amdgcn_s_barrier();                                                 \
  }

// STG_A/STG_B: stage k-half h of tile t into buffer (t&1)
#define STG_A(t, h)                                                               \
  { _Pragma("unroll")                                                             \
    for (int j = 0; j < 2; ++j)                                                   \
      __builtin_amdgcn_global_load_lds(                                           \
          (glob_u32_t*)(A + aOff[j] + (size_t)((t) * 64 + (h) * 32)),             \
          (lds_u32_t*)(smem + ((t) & 1) * 32768 + (h) * 16384 + ldsC[j]),         \
          16, 0, 0); }
#define STG_B(t, h)                                                               \
  { _Pragma("unroll")                                                             \
    for (int j = 0; j < 2; ++j)                                                   \
      __builtin_amdgcn_global_load_lds(                                           \
          (glob_u32_t*)(B + bOff[j] + (size_t)((t) * 64 + (h) * 32)),             \
          (lds_u32_t*)(smem + 65536 + ((t) & 1) * 32768 + (h) * 16384 + ldsC[j]), \
          16, 0, 0); }

#define EPOCH(T, S1, S2, W0, W2)                                                  \
  {                                                                               \
    const int b_ = (T) & 1;                                                       \
    /* ---- P0 : compute ks0/mh0, stage (T+1).A-h1 ---- */                        \
    if (S1) STG_A((T) + 1, 1);                                                    \
    asm volatile("s_waitcnt vmcnt(" W0 ")" ::: "memory");                         \
    __builtin_amdgcn_s_barrier();                                                 \
    RD_B(b_, 0); RD_A(b_, 0, 0);                                                  \
    PH_MFMA(0);                                                                   \
    /* ---- P1 : compute ks0/mh1, stage (T+1).B-h1 ---- */                        \
    RD_A(b_, 0, 1);                                                               \
    if (S1) STG_B((T) + 1, 1);                                                    \
    __builtin_amdgcn_s_barrier();                                                 \
    PH_MFMA(1);                                                                   \
    /* ---- P2 : compute ks1/mh0, stage (T+2).A-h0 ---- */                        \
    if (S2) STG_A((T) + 2, 0);                                                    \
    asm volatile("s_waitcnt vmcnt(" W2 ")" ::: "memory");                         \
    __builtin_amdgcn_s_barrier();                                                 \
    RD_B(b_, 1); RD_A(b_, 1, 0);                                                  \
    PH_MFMA(0);                                                                   \
    /* ---- P3 : compute ks1/mh1, stage (T+2).B-h0 ---- */                        \
    RD_A(b_, 1, 1);                                                               \
    if (S2) STG_B((T) + 2, 0);                                                    \
    __builtin_amdgcn_s_barrier();                                                 \
    PH_MFMA(1);                                                                   \
  }

__global__ __launch_bounds__(512)
void gemm_bt_256(const __bf16* __restrict__ A,
                 const __bf16* __restrict__ B,
                 const float* __restrict__ BIAS,
                 float* __restrict__ OUT,
                 const int M, const int N, const int K)
{
    extern __shared__ char smem[];   // 131072 B

    const int tid  = threadIdx.x;
    const int lane = tid & 63;
    const int wave = tid >> 6;

    // XCD-aware bijective swizzle (launcher guarantees gridDim.x % 8 == 0)
    const int cpx = gridDim.x >> 3;
    int bid = blockIdx.x;
    bid = (bid & 7) * cpx + (bid >> 3);

    const int nTn = N >> 8;
    const int m0  = (bid / nTn) << 8;
    const int n0  = (bid % nTn) << 8;

    const int wmRow = (wave >> 2) * 128;
    const int wnRow = (wave & 3) * 64;
    const int l15   = lane & 15;
    const int lhi   = lane >> 4;
    const int swz   = lhi ^ (l15 & 3);       // read-side chunk swizzle (r&3 == l15&3)

    f32x4 acc[8][4] = {};
    bf16x8 af[4], bfr[4];

    // per-thread staging addresses: chunk c = tid + 512j covers [256 rows][32 k]
    size_t aOff[2], bOff[2];
    int ldsC[2];
    #pragma unroll
    for (int j = 0; j < 2; ++j) {
        const int c   = tid + 512 * j;
        const int row = c >> 2;
        const int scc = (c & 3) ^ (row & 3);   // inverse (=same) involution as read
        aOff[j] = (size_t)(m0 + row) * K + scc * 8;
        bOff[j] = (size_t)(n0 + row) * K + scc * 8;
        ldsC[j] = c * 16;
    }

    // prologue: exact steady-state FIFO order
    STG_A(0, 0); STG_B(0, 0); STG_A(0, 1); STG_B(0, 1); STG_A(1, 0); STG_B(1, 0);

    const int kT = K >> 6;
    int t = 0;
    for (; t < kT - 2; ++t) EPOCH(t, true, true, "10", "10");
    EPOCH(t, true, false, "10", "8");  ++t;
    EPOCH(t, false, false, "4", "0");

    // epilogue: C/D layout col=lane&15, row=(lane>>4)*4+reg (m89-verified)
    const int cb = n0 + wnRow + l15;
    const int rb = m0 + wmRow + (lane >> 4) * 4;
    #pragma unroll
    for (int ni = 0; ni < 4; ++ni) {
        const float bv = BIAS[cb + ni * 16];
        #pragma unroll
        for (int mi = 0; mi < 8; ++mi)
            #pragma unroll
            for (int r = 0; r < 4; ++r)
                OUT[(size_t)(rb + mi * 16 + r) * N + cb + ni * 16] = acc[mi][ni][r] + bv;
    }
}

// ==================== Fallback: round-1 fused kernel (verified pass) ====================
constexpr int BM  = 128;
constexpr int BN  = 128;
constexpr int BK  = 64;
constexpr int LDK = 72;

__global__ __launch_bounds__(256, 2)
void gptq_gemm_fused(const float* __restrict__ X,
                     const unsigned int* __restrict__ QW,
                     const unsigned int* __restrict__ QZ,
                     const float* __restrict__ SC,
                     const float* __restrict__ BIAS,
                     float* __restrict__ OUT,
                     const int M, const int N, const int K)
{
    __shared__ __bf16 As[BM * LDK];
    __shared__ __bf16 Bs[BN * LDK];

    const int tid = threadIdx.x;
    const int nTn = N / BN;
    const int m0  = (blockIdx.x / nTn) * BM;
    const int n0  = (blockIdx.x % nTn) * BN;

    const int lane = tid & 63;
    const int wave = tid >> 6;
    const int wm   = (wave >> 1) * 64;
    const int wn   = (wave & 1) * 64;
    const int l15  = lane & 15;
    const int lk8  = (lane >> 4) * 8;

    const int a_kc = (tid & 15) * 4;
    const int a_r0 = tid >> 4;
    const int b_c  = tid & 127;
    const int b_r0 = tid >> 7;
    const int N8   = N >> 3;

    f32x4 acc[4][4] = {};
    float4 av[8];
    unsigned int bw[4];
    float scale, nzs;

    auto load_tile = [&](int kt_) {
        const int k0 = kt_ * BK;
        #pragma unroll
        for (int i = 0; i < 8; ++i)
            av[i] = *(const float4*)&X[(m0 + a_r0 + 16 * i) * K + k0 + a_kc];
        const int qr = k0 >> 3;
        #pragma unroll
        for (int i = 0; i < 4; ++i)
            bw[i] = QW[(qr + b_r0 + 2 * i) * N + n0 + b_c];
        const int g = k0 >> 7;
        scale = SC[g * N + n0 + b_c];
        const unsigned int qzv = QZ[g * N8 + ((n0 + b_c) >> 3)];
        const int z = (qzv >> (((n0 + b_c) & 7) * 4)) & 15;
        nzs = (float)z * scale;
    };

    load_tile(0);

    const int kTiles = K / BK;
    for (int kt = 0; kt < kTiles; ++kt) {
        __syncthreads();
        #pragma unroll
        for (int i = 0; i < 8; ++i) {
            bf16x4 v = { (__bf16)av[i].x, (__bf16)av[i].y,
                         (__bf16)av[i].z, (__bf16)av[i].w };
            *(bf16x4*)&As[(a_r0 + 16 * i) * LDK + a_kc] = v;
        }
        {
            const float s = scale, nz = nzs;
            #pragma unroll
            for (int i = 0; i < 4; ++i) {
                const unsigned int w32 = bw[i];
                bf16x8 v;
                #pragma unroll
                for (int j = 0; j < 8; ++j) {
                    const int w = (w32 >> (4 * j)) & 15;
                    v[j] = (__bf16)((float)w * s - nz);
                }
                *(bf16x8*)&Bs[b_c * LDK + (b_r0 + 2 * i) * 8] = v;
            }
        }
        __syncthreads();

        if (kt + 1 < kTiles) load_tile(kt + 1);

        #pragma unroll
        for (int ks = 0; ks < 2; ++ks) {
            bf16x8 af[4], bfr[4];
            #pragma unroll
            for (int mi = 0; mi < 4; ++mi)
                af[mi] = *(bf16x8*)&As[(wm + mi * 16 + l15) * LDK + ks * 32 + lk8];
            #pragma unroll
            for (int ni = 0; ni < 4; ++ni)
                bfr[ni] = *(bf16x8*)&Bs[(wn + ni * 16 + l15) * LDK + ks * 32 + lk8];
            #pragma unroll
            for (int mi = 0; mi < 4; ++mi)
                #pragma unroll
                for (int ni = 0; ni < 4; ++ni)
                    acc[mi][ni] = __builtin_amdgcn_mfma_f32_16x16x32_bf16(
                        af[mi], bfr[ni], acc[mi][ni], 0, 0, 0);
        }
    }

    const int cb = n0 + wn + l15;
    const int rb = m0 + wm + (lane >> 4) * 4;
    #pragma unroll
    for (int ni = 0; ni < 4; ++ni) {
        const float bv = BIAS[cb + ni * 16];
        #pragma unroll
        for (int mi = 0; mi < 4; ++mi)
            #pragma unroll
            for (int r = 0; r < 4; ++r)
                OUT[(size_t)(rb + mi * 16 + r) * N + cb + ni * 16] = acc[mi][ni][r] + bv;
    }
}

extern "C" void kernel_launch(void* const* d_in, const int* in_sizes, int n_in,
                              void* d_out, int out_size, void* d_ws, size_t ws_size,
                              hipStream_t stream) {
    const float*        x    = (const float*)d_in[0];
    const unsigned int* qw   = (const unsigned int*)d_in[1];
    const unsigned int* qz   = (const unsigned int*)d_in[2];
    const float*        sc   = (const float*)d_in[3];
    const float*        bias = (const float*)d_in[5];
    float*              out  = (float*)d_out;

    const int K = in_sizes[4];          // 4096 (g_idx length)
    const int N = in_sizes[5];          // 11008 (bias length)
    const int M = in_sizes[0] / K;      // 8192 tokens

    const size_t needA = (size_t)M * K * 2;
    const size_t needB = (size_t)N * K * 2;
    const int    nwg   = (M / 256) * (N / 256);
    const bool canSplit = (ws_size >= needA + needB) &&
                          (M % 256 == 0) && (N % 256 == 0) && (K % 128 == 0) &&
                          (K >= 256) && ((nwg & 7) == 0);

    if (canSplit) {
        __bf16* xb = (__bf16*)d_ws;
        __bf16* wt = (__bf16*)((char*)d_ws + needA);
        const long long n8 = (long long)M * K / 8;
        cvt_x_bf16<<<(int)((n8 + 255) / 256), 256, 0, stream>>>(x, xb, n8);
        dequant_wt<<<(N / 256) * (K / 64), 256, 0, stream>>>(qw, qz, sc, wt, N, K);
        (void)hipFuncSetAttribute((const void*)gemm_bt_256,
                                  hipFuncAttributeMaxDynamicSharedMemorySize, 131072);
        gemm_bt_256<<<nwg, 512, 131072, stream>>>(xb, wt, bias, out, M, N, K);
    } else {
        const int nwg128 = (M / 128) * (N / 128);
        gptq_gemm_fused<<<nwg128, 256, 0, stream>>>(x, qw, qz, sc, bias, out, M, N, K);
    }
}